// Round 12
// baseline (52.966 us; speedup 1.0000x reference)
//
#include <hip/hip_runtime.h>
#include <stdint.h>

#define NT 4096
#define L2E 1.44269504f

typedef short s16x8 __attribute__((ext_vector_type(8)));
typedef short s16x4 __attribute__((ext_vector_type(4)));
typedef float f32x16 __attribute__((ext_vector_type(16)));
typedef float f32x4 __attribute__((ext_vector_type(4)));

__device__ __forceinline__ unsigned short f2bf(float f) {
  unsigned int u = __float_as_uint(f);
  u = u + 0x7FFFu + ((u >> 16) & 1u);   // RNE to bf16
  return (unsigned short)(u >> 16);
}

// pack 16 f32 p-values into two P A-fragments (verified R2..R6 map)
__device__ __forceinline__ void pack_pa(const float* p, s16x8* pa) {
  unsigned w8[8];
#pragma unroll
  for (int m = 0; m < 8; ++m)
    asm("v_cvt_pk_bf16_f32 %0, %1, %2" : "=v"(w8[m]) : "v"(p[2 * m]), "v"(p[2 * m + 1]));
  unsigned a0 = w8[0], b0 = w8[2]; asm("v_permlane32_swap_b32 %0, %1" : "+v"(a0), "+v"(b0));
  unsigned a1 = w8[1], b1 = w8[3]; asm("v_permlane32_swap_b32 %0, %1" : "+v"(a1), "+v"(b1));
  unsigned c0 = w8[4], d0 = w8[6]; asm("v_permlane32_swap_b32 %0, %1" : "+v"(c0), "+v"(d0));
  unsigned c1 = w8[5], d1 = w8[7]; asm("v_permlane32_swap_b32 %0, %1" : "+v"(c1), "+v"(d1));
  union PW { unsigned u[4]; s16x8 v; } q0, q1;
  q0.u[0] = a0; q0.u[1] = a1; q0.u[2] = b0; q0.u[3] = b1;
  q1.u[0] = c0; q1.u[1] = c1; q1.u[2] = d0; q1.u[3] = d1;
  pa[0] = q0.v; pa[1] = q1.v;
}

// merge helpers; scr layout f32 [32 i][132 c-padded]; i = crow(r,hi), c = cb*32+lc
__device__ __forceinline__ void merge_write(float* scr, const f32x16 (&acc)[4],
                                            int lc, int hi) {
#pragma unroll
  for (int cb = 0; cb < 4; ++cb)
#pragma unroll
    for (int r = 0; r < 16; ++r) {
      int i = (r & 3) + 8 * (r >> 2) + 4 * hi;
      scr[i * 132 + cb * 32 + lc] = acc[cb][r];
    }
}
__device__ __forceinline__ void merge_add(const float* scr, f32x16 (&acc)[4],
                                          int lc, int hi) {
#pragma unroll
  for (int cb = 0; cb < 4; ++cb)
#pragma unroll
    for (int r = 0; r < 16; ++r) {
      int i = (r & 3) + 8 * (r >> 2) + 4 * hi;
      acc[cb][r] += scr[i * 132 + cb * 32 + lc];
    }
}

// ============================================================================
// Projection (verified): [wv(128); wq(16); wk(16)*log2e] @ x.
// grid 256 = b(4) x ntile64. qws/kws bf16 [b][n][16]; vfrag bf16 [b][jt][c][hi][8j]
// ============================================================================
__global__ __launch_bounds__(512, 2) void proj_kern(
    const float* __restrict__ x,
    const float* __restrict__ wq, const float* __restrict__ bq,
    const float* __restrict__ wk, const float* __restrict__ bk,
    const float* __restrict__ wv, const float* __restrict__ bv,
    short* __restrict__ qws, short* __restrict__ kws, short* __restrict__ vfrag) {
  __shared__ __align__(16) unsigned short w_s[160 * 128];
  __shared__ __align__(16) unsigned short xv_s[128 * 72];

  int t = threadIdx.x;
  int blk = blockIdx.x;
  int b = blk >> 6;
  int n0 = (blk & 63) * 64;

  for (int i4 = t; i4 < 5120; i4 += 512) {
    int row = i4 >> 5, ka = (i4 & 31) * 4;
    f32x4 v;
    float sc = 1.0f;
    if (row < 128)      v = *(const f32x4*)(wv + row * 128 + ka);
    else if (row < 144) v = *(const f32x4*)(wq + (row - 128) * 128 + ka);
    else              { v = *(const f32x4*)(wk + (row - 144) * 128 + ka); sc = L2E; }
    s16x4 o;
#pragma unroll
    for (int j = 0; j < 4; ++j) o[j] = (short)f2bf(v[j] * sc);
    unsigned byt = ((unsigned)(ka * 2)) ^ (((unsigned)row & 7u) << 4);
    *(s16x4*)((char*)w_s + row * 256 + byt) = o;
  }
  {
    int cL = t >> 4, nn4 = (t & 15) * 4;
    for (int cc = 0; cc < 128; cc += 32) {
      int c = cc + cL;
      f32x4 v = *(const f32x4*)(x + ((size_t)b * 128 + c) * NT + n0 + nn4);
      s16x4 o;
#pragma unroll
      for (int j = 0; j < 4; ++j) o[j] = (short)f2bf(v[j]);
      *(s16x4*)(xv_s + c * 64 + nn4) = o;
    }
  }
  __syncthreads();

  int w = t >> 6, lane = t & 63, lc = lane & 31, hi = lane >> 5;
  int rblk = w >> 1, nc = w & 1;
  int nn = nc * 32 + lc;

  f32x16 zf = {0.f,0.f,0.f,0.f,0.f,0.f,0.f,0.f,0.f,0.f,0.f,0.f,0.f,0.f,0.f,0.f};
  f32x16 acc = zf, acc2 = zf;

#pragma unroll
  for (int kk = 0; kk < 8; ++kk) {
    int kb0 = kk * 16 + hi * 8;
    s16x8 xf;
#pragma unroll
    for (int e = 0; e < 8; ++e) xf[e] = (short)xv_s[(kb0 + e) * 64 + nn];
    unsigned byt = ((unsigned)(kk * 32 + hi * 16)) ^ (((unsigned)lc & 7u) << 4);
    s16x8 af = *(const s16x8*)((const char*)w_s + (rblk * 32 + lc) * 256 + byt);
    acc = __builtin_amdgcn_mfma_f32_32x32x16_bf16(af, xf, acc, 0, 0, 0);
    if (rblk == 3) {
      s16x8 af2 = *(const s16x8*)((const char*)w_s + (128 + lc) * 256 + byt);
      acc2 = __builtin_amdgcn_mfma_f32_32x32x16_bf16(af2, xf, acc2, 0, 0, 0);
    }
  }

  if (rblk == 3) {
    size_t nidx = ((size_t)b * NT + n0 + nn) * 16;
    s16x4 q0, q1, k0, k1;
#pragma unroll
    for (int j = 0; j < 4; ++j) {
      q0[j] = (short)f2bf(acc2[j]      + bq[j + 4 * hi]);
      q1[j] = (short)f2bf(acc2[j + 4]  + bq[j + 8 + 4 * hi]);
      k0[j] = (short)f2bf(acc2[j + 8]  + bk[j + 4 * hi] * L2E);
      k1[j] = (short)f2bf(acc2[j + 12] + bk[j + 8 + 4 * hi] * L2E);
    }
    *(s16x4*)(qws + nidx + 4 * hi)     = q0;
    *(s16x4*)(qws + nidx + 8 + 4 * hi) = q1;
    *(s16x4*)(kws + nidx + 4 * hi)     = k0;
    *(s16x4*)(kws + nidx + 8 + 4 * hi) = k1;
  }

  __syncthreads();
#pragma unroll
  for (int r = 0; r < 16; ++r) {
    int c = rblk * 32 + (r & 3) + 8 * (r >> 2) + 4 * hi;
    xv_s[c * 72 + nn] = f2bf(acc[r] + bv[c]);
  }
  __syncthreads();
#pragma unroll
  for (int p = 0; p < 2; ++p) {
    int gid = t + p * 512;
    int c = gid & 127, ng = gid >> 7;
    s16x8 v = *(const s16x8*)(xv_s + c * 72 + ng * 8);
    size_t idx = (((size_t)b * 256 + (n0 >> 4) + (ng >> 1)) * 128 + c) * 16 + (ng & 1) * 8;
    *(s16x8*)(vfrag + idx) = v;
  }
}

// ============================================================================
// Flash attention PARTIAL: grid 1024 = b(4) x it(128) x jsplit(2).
// 256 thr = 4 waves = 4 private j-streams (512 j, 16 steps). Slim state ->
// 12-16 waves/CU. 2-deep e-pipeline (QK(t+1) overlaps softmax/PV(t)).
// Writes raw D-sums (f32) + L-sums; merge_kern normalizes.
// ============================================================================
__global__ __launch_bounds__(256) void attn_part(
    const short* __restrict__ qws, const short* __restrict__ kws, const short* __restrict__ vfrag,
    float* __restrict__ Dp, float* __restrict__ Lp) {
  __shared__ __align__(16) unsigned char lds[34432];
  // rg0 @0 (16896B f32[32][132]), rg1 @16896; lsc @33792 (4*32 f32)

  int g = blockIdx.x;
  int gg = (g & 7) * 128 + (g >> 3);  // XCD swizzle; js-pair lands on same XCD
  int b = gg >> 8;
  int it = (gg >> 1) & 127;
  int js = gg & 1;
  int t = threadIdx.x;
  int w = t >> 6, lane = t & 63, lc = lane & 31, hi = lane >> 5;
  int jt0 = js * 2048 + w * 512;

  const short* qb = qws + (size_t)b * NT * 16;
  const short* kb = kws + (size_t)b * NT * 16;
  const short* vfb = vfrag + (size_t)b * 256 * 128 * 16;

  s16x8 qf = *(const s16x8*)(qb + (size_t)(it * 32 + lc) * 16 + hi * 8);

  f32x16 zf = {0.f,0.f,0.f,0.f,0.f,0.f,0.f,0.f,0.f,0.f,0.f,0.f,0.f,0.f,0.f,0.f};
  f32x16 acc[4];
#pragma unroll
  for (int j = 0; j < 4; ++j) acc[j] = zf;
  float lsum = 0.f;

  // pipeline prologue
  s16x8 kfA = *(const s16x8*)(kb + (size_t)(jt0 + lc) * 16 + hi * 8);
  f32x16 eA = __builtin_amdgcn_mfma_f32_32x32x16_bf16(kfA, qf, zf, 0, 0, 0);
  s16x8 kfB = *(const s16x8*)(kb + (size_t)(jt0 + 32 + lc) * 16 + hi * 8);
  f32x16 eB = zf;

  auto body = [&](int st, f32x16& eCur, f32x16& eNxt, s16x8& kfNxt, s16x8& kfFar) {
    int jtb = (jt0 >> 4) + st * 2;
    s16x8 vc[2][4];
#pragma unroll
    for (int sl = 0; sl < 2; ++sl)
#pragma unroll
      for (int cb = 0; cb < 4; ++cb)
        vc[sl][cb] = *(const s16x8*)(vfb + ((size_t)(jtb + sl) * 128 + cb * 32 + lc) * 16 + hi * 8);

#pragma unroll
    for (int r = 0; r < 16; ++r) eCur[r] = __builtin_amdgcn_exp2f(eCur[r]);
    float a0 = 0.f;
#pragma unroll
    for (int r = 0; r < 16; ++r) a0 += eCur[r];
    lsum += a0;
    s16x8 pa[2];
    pack_pa((const float*)&eCur, pa);

    if (st < 15)
      eNxt = __builtin_amdgcn_mfma_f32_32x32x16_bf16(kfNxt, qf, zf, 0, 0, 0);
    if (st < 14)
      kfFar = *(const s16x8*)(kb + (size_t)(jt0 + (st + 2) * 32 + lc) * 16 + hi * 8);

    __builtin_amdgcn_s_setprio(1);
#pragma unroll
    for (int cb = 0; cb < 4; ++cb)
      acc[cb] = __builtin_amdgcn_mfma_f32_32x32x16_bf16(pa[0], vc[0][cb], acc[cb], 0, 0, 0);
#pragma unroll
    for (int cb = 0; cb < 4; ++cb)
      acc[cb] = __builtin_amdgcn_mfma_f32_32x32x16_bf16(pa[1], vc[1][cb], acc[cb], 0, 0, 0);
    __builtin_amdgcn_s_setprio(0);
  };

  for (int sp = 0; sp < 8; ++sp) {
    body(2 * sp,     eA, eB, kfB, kfA);
    body(2 * sp + 1, eB, eA, kfA, kfB);
  }

  // ---- merge 4 private streams (raw sums) ----
  float* rg0 = (float*)lds;
  float* rg1 = (float*)(lds + 16896);
  float* lsc = (float*)(lds + 33792);

  float lf = lsum + __shfl_xor(lsum, 32);
  if (hi == 0) lsc[w * 32 + lc] = lf;
  if (w == 2) merge_write(rg0, acc, lc, hi);
  if (w == 3) merge_write(rg1, acc, lc, hi);
  __syncthreads();                                   // B1
  if (t < 32) {
    float L = lsc[t] + lsc[32 + t] + lsc[64 + t] + lsc[96 + t];
    Lp[((size_t)js * 4 + b) * NT + it * 32 + t] = L;
  }
  if (w == 0) merge_add(rg0, acc, lc, hi);
  if (w == 1) merge_add(rg1, acc, lc, hi);
  __syncthreads();                                   // B2
  if (w == 1) merge_write(rg0, acc, lc, hi);
  __syncthreads();                                   // B3
  if (w == 0) { merge_add(rg0, acc, lc, hi); merge_write(rg0, acc, lc, hi); }
  __syncthreads();                                   // B4

  // ---- write raw D partial stripe, coalesced ----
  int cc = t >> 1, ih = (t & 1) * 16;
  float* dp = Dp + (((size_t)js * 4 + b) * 128 + cc) * NT + it * 32 + ih;
#pragma unroll
  for (int q2 = 0; q2 < 4; ++q2) {
    f32x4 ov;
#pragma unroll
    for (int j = 0; j < 4; ++j) ov[j] = rg0[(ih + q2 * 4 + j) * 132 + cc];
    *(f32x4*)(dp + q2 * 4) = ov;
  }
}

// ============================================================================
// Merge: out = gamma * (D0+D1)/(L0+L1) + x. Fully coalesced f32x4.
// ============================================================================
__global__ __launch_bounds__(256) void merge_kern(
    const float* __restrict__ Dp, const float* __restrict__ Lp,
    const float* __restrict__ x, const float* __restrict__ gp,
    float* __restrict__ out) {
  int idx = blockIdx.x * 256 + threadIdx.x;
  size_t off = (size_t)idx * 4;
  int n = (int)(off & (NT - 1));
  int b = (int)(off >> 19);
  float gam = gp[0];
  f32x4 d0 = *(const f32x4*)(Dp + off);
  f32x4 d1 = *(const f32x4*)(Dp + (size_t)4 * 128 * NT + off);
  f32x4 l0 = *(const f32x4*)(Lp + (size_t)b * NT + n);
  f32x4 l1 = *(const f32x4*)(Lp + (size_t)4 * NT + (size_t)b * NT + n);
  f32x4 xv = *(const f32x4*)(x + off);
  f32x4 ov;
#pragma unroll
  for (int j = 0; j < 4; ++j)
    ov[j] = gam * (d0[j] + d1[j]) / (l0[j] + l1[j]) + xv[j];
  *(f32x4*)(out + off) = ov;
}

extern "C" void kernel_launch(void* const* d_in, const int* in_sizes, int n_in,
                              void* d_out, int out_size, void* d_ws, size_t ws_size,
                              hipStream_t stream) {
  const float* x     = (const float*)d_in[0];
  const float* wq    = (const float*)d_in[1];
  const float* bq    = (const float*)d_in[2];
  const float* wk    = (const float*)d_in[3];
  const float* bk    = (const float*)d_in[4];
  const float* wv    = (const float*)d_in[5];
  const float* bv    = (const float*)d_in[6];
  const float* gamma = (const float*)d_in[7];
  float* out = (float*)d_out;

  short* qws   = (short*)d_ws;                        // 512 KB
  short* kws   = qws + (size_t)4 * NT * 16;           // 512 KB
  short* vfrag = kws + (size_t)4 * NT * 16;           // 4 MB
  float* Dp    = (float*)(vfrag + (size_t)4 * 256 * 128 * 16);  // 2 x 8 MB f32
  float* Lp    = Dp + (size_t)2 * 4 * 128 * NT;       // 32K f32

  proj_kern<<<256, 512, 0, stream>>>(x, wq, bq, wk, bk, wv, bv, qws, kws, vfrag);
  attn_part<<<1024, 256, 0, stream>>>(qws, kws, vfrag, Dp, Lp);
  merge_kern<<<2048, 256, 0, stream>>>(Dp, Lp, x, gamma, out);
}